// Round 5
// baseline (62.141 us; speedup 1.0000x reference)
//
#include <hip/hip_runtime.h>
#include <hip/hip_bf16.h>
#include <math.h>

#define IN_FEAT 4096
#define OUT_FEAT 4096
#define NCOMP 256
#define BATCH 4096
#define TWO_PI_F 6.28318530717958647692f

typedef __attribute__((ext_vector_type(8))) short short8;
typedef __attribute__((ext_vector_type(8))) __bf16 bf16x8;
typedef __attribute__((ext_vector_type(4))) float f32x4;
typedef __attribute__((ext_vector_type(16))) float f32x16;

// round-to-nearest-even f32 -> bf16
__device__ __forceinline__ ushort f2b(float f) {
  union { float f; unsigned u; } v; v.f = f;
  unsigned r = (v.u + 0x7fffu + ((v.u >> 16) & 1u)) >> 16;
  return (ushort)r;
}

__device__ __forceinline__ float b2f(short s) {
  union { unsigned u; float f; } v; v.u = ((unsigned)(ushort)s) << 16;
  return v.f;
}

__device__ __forceinline__ bf16x8 ld_frag(const void* p) {
  short8 s = *(const short8*)p;
  return __builtin_bit_cast(bf16x8, s);
}

__device__ __forceinline__ short8 cvt8(float4 a, float4 b) {
  short8 h;
  h[0] = (short)f2b(a.x); h[1] = (short)f2b(a.y);
  h[2] = (short)f2b(a.z); h[3] = (short)f2b(a.w);
  h[4] = (short)f2b(b.x); h[5] = (short)f2b(b.y);
  h[6] = (short)f2b(b.z); h[7] = (short)f2b(b.w);
  return h;
}

__device__ __forceinline__ void gload_lds16(const ushort* g, ushort* l) {
  __builtin_amdgcn_global_load_lds(
      (const __attribute__((address_space(1))) void*)g,
      (__attribute__((address_space(3))) void*)l, 16, 0, 0);
}

// ---------------------------------------------------------------- prep
__global__ __launch_bounds__(256) void prep_kernel(
    const float* __restrict__ mus, const float* __restrict__ lvs,
    const float* __restrict__ w,
    ushort* __restrict__ Gt, ushort* __restrict__ GoT) {
  int idx = blockIdx.x * 256 + threadIdx.x;
  if (idx < NCOMP * IN_FEAT) {
    int m = idx >> 12, i = idx & (IN_FEAT - 1);
    float v = expf(lvs[2 * m]);
    float d = (float)i * (1.0f / (IN_FEAT - 1)) - mus[2 * m];
    float g = expf(-d * d * (0.5f / v)) * rsqrtf(TWO_PI_F * v) * w[m];
    Gt[idx] = f2b(g);
  } else {
    idx -= NCOMP * IN_FEAT;
    int o = idx >> 8, m = idx & (NCOMP - 1);
    float v = expf(lvs[2 * m + 1]);
    float d = (float)o * (1.0f / (OUT_FEAT - 1)) - mus[2 * m + 1];
    float g = expf(-d * d * (0.5f / v)) * rsqrtf(TWO_PI_F * v);
    GoT[idx] = f2b(g);
  }
}

// ---------------------------------------------------------------- GEMM1
// Cpart[split][4096][256](bf16) = x[64-band, kchunk] @ Gt^T
// 32x32x16 MFMA. BM=64, BN=256; wave w: m[0,64) x n[w*64, w*64+64) as 2x2
// 32x32 frags. Stage=32k, dbuf (20 KB/buf -> 40 KB -> 4 blocks/CU).
template<int NS>
__global__ __launch_bounds__(256, 4) void gemm1_kernel(
    const float* __restrict__ x, const ushort* __restrict__ Gt,
    ushort* __restrict__ Cpart) {
  constexpr int KR = IN_FEAT / NS;
  constexpr int NT = KR / 32;
  // per buf: B = 256n x 32k = 16 KB at +0, A = 64m x 32k = 4 KB at +16 KB
  __shared__ __align__(16) ushort lds[2 * 10240];  // 40 KB
  const int tid = threadIdx.x, wid = tid >> 6, lane = tid & 63;
  const int m0 = blockIdx.x * 64;
  const int kb0 = blockIdx.y * KR;
  const int r32 = lane & 31, h = lane >> 5;

  f32x16 acc[2][2] = {};  // [mi][nj], each 32x32

  // B staging: 16 chunks of 1 KB (16 n-rows x 64 B); 4 per wave; pre-swizzled src
  const int brow = lane >> 2;
  const int bswz = (((lane & 3) ^ ((lane >> 3) & 3)) << 3);  // ushort units
  // A staging: 64 rows x 32 k f32, 8 f32/thread, swizzled ds_write
  const int arow = tid >> 2, aslot = tid & 3;
  const float* asrc = &x[(size_t)(m0 + arow) * IN_FEAT + kb0 + aslot * 8];
  const int abyte = arow * 64 + ((aslot << 4) ^ (((arow >> 1) & 3) << 4));
  // fragment-read swizzle: logical slot (2s+h) -> lin slot ^ ((r32>>1)&3)
  const int sw0 = (h << 4) ^ (((r32 >> 1) & 3) << 4);

  #define STAGE_B(buf, kb)                                                   \
    _Pragma("unroll")                                                        \
    for (int q = 0; q < 4; ++q) {                                            \
      int nb = wid * 4 + q;                                                  \
      gload_lds16(&Gt[(size_t)(nb * 16 + brow) * IN_FEAT + (kb) + bswz],     \
                  &lds[(buf) * 10240 + nb * 512]);                           \
    }

  // prologue
  {
    float4 a0 = *(const float4*)asrc;
    float4 a1 = *(const float4*)(asrc + 4);
    STAGE_B(0, kb0)
    *(short8*)((char*)lds + 16384 + abyte) = cvt8(a0, a1);
  }
  __syncthreads();

  for (int t = 0; t < NT; ++t) {
    float4 px0, px1;
    if (t + 1 < NT) {  // x first (HBM latency), then B (L2-hot)
      px0 = *(const float4*)(asrc + (t + 1) * 32);
      px1 = *(const float4*)(asrc + (t + 1) * 32 + 4);
      STAGE_B((t + 1) & 1, kb0 + (t + 1) * 32)
    }
    const char* base = (const char*)lds + (t & 1) * 20480;
    const char* Ab = base + 16384;
    #pragma unroll
    for (int s = 0; s < 2; ++s) {
      const int off = sw0 ^ (s << 5);
      bf16x8 a0 = ld_frag(Ab + r32 * 64 + off);
      bf16x8 a1 = ld_frag(Ab + (32 + r32) * 64 + off);
      bf16x8 b0 = ld_frag(base + (wid * 64 + r32) * 64 + off);
      bf16x8 b1 = ld_frag(base + (wid * 64 + 32 + r32) * 64 + off);
      acc[0][0] = __builtin_amdgcn_mfma_f32_32x32x16_bf16(a0, b0, acc[0][0], 0, 0, 0);
      acc[0][1] = __builtin_amdgcn_mfma_f32_32x32x16_bf16(a0, b1, acc[0][1], 0, 0, 0);
      acc[1][0] = __builtin_amdgcn_mfma_f32_32x32x16_bf16(a1, b0, acc[1][0], 0, 0, 0);
      acc[1][1] = __builtin_amdgcn_mfma_f32_32x32x16_bf16(a1, b1, acc[1][1], 0, 0, 0);
    }
    if (t + 1 < NT)
      *(short8*)((char*)lds + ((t + 1) & 1) * 20480 + 16384 + abyte) =
          cvt8(px0, px1);
    __syncthreads();
  }
  #undef STAGE_B

  ushort* Cp = Cpart + (size_t)blockIdx.y * ((size_t)BATCH * NCOMP);
  #pragma unroll
  for (int mi = 0; mi < 2; ++mi)
    #pragma unroll
    for (int nj = 0; nj < 2; ++nj)
      #pragma unroll
      for (int g = 0; g < 16; ++g) {
        int row = m0 + mi * 32 + (g & 3) + 8 * (g >> 2) + 4 * h;
        int col = wid * 64 + nj * 32 + r32;
        Cp[(size_t)row * NCOMP + col] = f2b(acc[mi][nj][g]);
      }
}

// ---------------------------------------------------------------- reduce
template<int NS>
__global__ __launch_bounds__(256) void reduce_kernel(ushort* __restrict__ Cp) {
  size_t i = ((size_t)blockIdx.x * 256 + threadIdx.x) * 8;
  float s[8] = {};
  #pragma unroll
  for (int p = 0; p < NS; ++p) {
    short8 v = *(const short8*)&Cp[(size_t)p * BATCH * NCOMP + i];
    #pragma unroll
    for (int e = 0; e < 8; ++e) s[e] += b2f(v[e]);
  }
  short8 hh;
  #pragma unroll
  for (int e = 0; e < 8; ++e) hh[e] = (short)f2b(s[e]);
  *(short8*)&Cp[i] = hh;
}

// ---------------------------------------------------------------- GEMM2
// out[4096][4096](f32) = (Cb @ GoT^T) * scale; 32x32x16 MFMA.
// BM=BN=128; wave (wr,wc) owns 64x64 as 2x2 32x32 frags. Stage=32k, dbuf 32 KB.
__global__ __launch_bounds__(256, 4) void gemm2_kernel(
    const ushort* __restrict__ Cb, const ushort* __restrict__ GoT,
    const float* __restrict__ w, float* __restrict__ out) {
  __shared__ __align__(16) ushort lds[2 * 8192];  // per buf: A 8 KB, B 8 KB
  const int tid = threadIdx.x, wid = tid >> 6, lane = tid & 63;
  const int m0 = blockIdx.y * 128, n0 = blockIdx.x * 128;
  const int wr = (wid >> 1) * 64, wc = (wid & 1) * 64;
  const int r32 = lane & 31, h = lane >> 5;

  // fold wsum: per-wave butterfly over the 256 weights
  float4 wv = *(const float4*)&w[lane * 4];
  float s = wv.x + wv.y + wv.z + wv.w;
  #pragma unroll
  for (int off = 32; off > 0; off >>= 1) s += __shfl_xor(s, off);
  const float scale = 1.0f / ((float)IN_FEAT * s);

  const int brow = lane >> 2;
  const int bswz = (((lane & 3) ^ ((lane >> 3) & 3)) << 3);
  const int sw0 = (h << 4) ^ (((r32 >> 1) & 3) << 4);

  f32x16 acc[2][2] = {};

  #define STAGE2(buf, k0)                                                    \
    _Pragma("unroll")                                                        \
    for (int q = 0; q < 2; ++q) {                                            \
      int c = wid * 2 + q;                                                   \
      int row = c * 16 + brow;                                               \
      gload_lds16(&Cb[(size_t)(m0 + row) * NCOMP + (k0) + bswz],             \
                  &lds[(buf) * 8192 + c * 512]);                             \
      gload_lds16(&GoT[(size_t)(n0 + row) * NCOMP + (k0) + bswz],            \
                  &lds[(buf) * 8192 + 4096 + c * 512]);                      \
    }

  STAGE2(0, 0)
  __syncthreads();

  for (int t = 0; t < 8; ++t) {
    if (t < 7) STAGE2((t + 1) & 1, (t + 1) * 32)
    const char* base = (const char*)lds + (t & 1) * 16384;
    const char* Bb = base + 8192;
    #pragma unroll
    for (int s2 = 0; s2 < 2; ++s2) {
      const int off = sw0 ^ (s2 << 5);
      bf16x8 a0 = ld_frag(base + (wr + r32) * 64 + off);
      bf16x8 a1 = ld_frag(base + (wr + 32 + r32) * 64 + off);
      bf16x8 b0 = ld_frag(Bb + (wc + r32) * 64 + off);
      bf16x8 b1 = ld_frag(Bb + (wc + 32 + r32) * 64 + off);
      acc[0][0] = __builtin_amdgcn_mfma_f32_32x32x16_bf16(a0, b0, acc[0][0], 0, 0, 0);
      acc[0][1] = __builtin_amdgcn_mfma_f32_32x32x16_bf16(a0, b1, acc[0][1], 0, 0, 0);
      acc[1][0] = __builtin_amdgcn_mfma_f32_32x32x16_bf16(a1, b0, acc[1][0], 0, 0, 0);
      acc[1][1] = __builtin_amdgcn_mfma_f32_32x32x16_bf16(a1, b1, acc[1][1], 0, 0, 0);
    }
    __syncthreads();
  }
  #undef STAGE2

  #pragma unroll
  for (int mi = 0; mi < 2; ++mi)
    #pragma unroll
    for (int nj = 0; nj < 2; ++nj)
      #pragma unroll
      for (int g = 0; g < 16; ++g) {
        int row = m0 + wr + mi * 32 + (g & 3) + 8 * (g >> 2) + 4 * h;
        int col = n0 + wc + nj * 32 + r32;
        out[(size_t)row * OUT_FEAT + col] = acc[mi][nj][g] * scale;
      }
}

// ---------------------------------------------------------------- launch
extern "C" void kernel_launch(void* const* d_in, const int* in_sizes, int n_in,
                              void* d_out, int out_size, void* d_ws, size_t ws_size,
                              hipStream_t stream) {
  const float* x   = (const float*)d_in[0];
  const float* mus = (const float*)d_in[1];
  const float* lvs = (const float*)d_in[2];
  const float* w   = (const float*)d_in[3];
  float* out = (float*)d_out;

  ushort* Gt  = (ushort*)d_ws;                      // [256][4096] bf16, 2 MiB
  ushort* GoT = Gt  + (size_t)NCOMP * IN_FEAT;      // [4096][256] bf16, 2 MiB
  ushort* Cpart = GoT + (size_t)OUT_FEAT * NCOMP;   // NS x 2 MiB; Cb = Cpart[0]

  const size_t MiB = 1024 * 1024;
  int nsplit = 16;
  while (nsplit > 1 && ws_size < 4 * MiB + (size_t)nsplit * 2 * MiB) nsplit >>= 1;

  prep_kernel<<<(NCOMP * IN_FEAT + OUT_FEAT * NCOMP) / 256, 256, 0, stream>>>(
      mus, lvs, w, Gt, GoT);

  dim3 g1(BATCH / 64, nsplit);
  switch (nsplit) {
    case 16: gemm1_kernel<16><<<g1, 256, 0, stream>>>(x, Gt, Cpart);
             reduce_kernel<16><<<BATCH * NCOMP / 8 / 256, 256, 0, stream>>>(Cpart);
             break;
    case 8:  gemm1_kernel<8><<<g1, 256, 0, stream>>>(x, Gt, Cpart);
             reduce_kernel<8><<<BATCH * NCOMP / 8 / 256, 256, 0, stream>>>(Cpart);
             break;
    case 4:  gemm1_kernel<4><<<g1, 256, 0, stream>>>(x, Gt, Cpart);
             reduce_kernel<4><<<BATCH * NCOMP / 8 / 256, 256, 0, stream>>>(Cpart);
             break;
    case 2:  gemm1_kernel<2><<<g1, 256, 0, stream>>>(x, Gt, Cpart);
             reduce_kernel<2><<<BATCH * NCOMP / 8 / 256, 256, 0, stream>>>(Cpart);
             break;
    default: gemm1_kernel<1><<<g1, 256, 0, stream>>>(x, Gt, Cpart);
             break;
  }

  gemm2_kernel<<<dim3(OUT_FEAT / 128, BATCH / 128), 256, 0, stream>>>(
      Cpart, GoT, w, out);
}